// Round 5
// baseline (268.029 us; speedup 1.0000x reference)
//
#include <hip/hip_runtime.h>

// Hex conv:  y[h,w,f] = relu( bias[f] + sum_taps x[h+dr, w+dc, c] * K[kr,kc][c][f] )
// parity p = h&1:
//   p==0 (7 taps): (dr,dc,kr,kc) = (0,0,0,1)(0,1,0,2)(1,-1,1,0)(1,0,1,1)(1,1,1,2)(2,0,2,1)(2,1,2,2)
//   p==1 (4 taps): (0,-1,0,1)(0,0,0,2)(1,-1,2,1)(1,0,2,2)
// x: (16,128,128,128) fp32 NHWC; K: (3,3,128,256) fp32 HWIO; bias: (256,) fp32.
// out: (16,128,128,256) FLOAT32  <-- the round-0..4 bug: out is fp32, not bf16.

#define N_  16
#define H_  128
#define W_  128
#define C_  128
#define F_  256

typedef short bf16x8 __attribute__((ext_vector_type(8)));  // 8 bf16 in 4 VGPRs
typedef float f32x4  __attribute__((ext_vector_type(4)));

__device__ __forceinline__ unsigned int bf_bits(float f) {
  unsigned int u = __float_as_uint(f);
  return (u + 0x7FFFu + ((u >> 16) & 1u)) >> 16;   // RNE fp32 -> bf16
}
__device__ __forceinline__ unsigned int pack2(float a, float b) {
  return bf_bits(a) | (bf_bits(b) << 16);
}

__device__ __forceinline__ void tap_info(int t, int& dr, int& dc, int& kr, int& kc) {
  switch (t) {
    case 0:  dr = 0; dc = 0;  kr = 0; kc = 1; break;
    case 1:  dr = 0; dc = 1;  kr = 0; kc = 2; break;
    case 2:  dr = 1; dc = -1; kr = 1; kc = 0; break;
    case 3:  dr = 1; dc = 0;  kr = 1; kc = 1; break;
    case 4:  dr = 1; dc = 1;  kr = 1; kc = 2; break;
    case 5:  dr = 2; dc = 0;  kr = 2; kc = 1; break;
    case 6:  dr = 2; dc = 1;  kr = 2; kc = 2; break;
    case 7:  dr = 0; dc = -1; kr = 0; kc = 1; break;
    case 8:  dr = 0; dc = 0;  kr = 0; kc = 2; break;
    case 9:  dr = 1; dc = -1; kr = 2; kc = 1; break;
    default: dr = 1; dc = 0;  kr = 2; kc = 2; break;
  }
}

// ---------------- prep: packed transposed weights ----------------
// wt[t][f][c] (c contiguous, bf16 bits) = kernel[kr(t)][kc(t)][c][f]
__global__ __launch_bounds__(256) void build_w_kernel(
    const float* __restrict__ k, unsigned short* __restrict__ wt) {
  int tid = blockIdx.x * 256 + threadIdx.x;
  if (tid >= 11 * F_ * C_) return;
  int c = tid & 127;
  int f = (tid >> 7) & 255;
  int t = tid >> 15;
  int dr, dc, kr, kc;
  tap_info(t, dr, dc, kr, kc);
  float v = k[((kr * 3 + kc) * C_ + c) * F_ + f];
  wt[tid] = (unsigned short)bf_bits(v);
}

// ---------------- main conv: implicit GEMM, MFMA 16x16x32 bf16 ----------------
// block = 256 thr (4 waves); tile = 64(w) x 128(f); K-step = 64 channels
// LDS: A [64 rows][128B] @0 (8KB), B [128 rows][128B] @8192 (16KB) -> 24KB
// 16B groups within each row XOR-swizzled by (row&7) on BOTH write and read.
__global__ __launch_bounds__(256) void hconv_kernel(
    const float* __restrict__ x,
    const unsigned short* __restrict__ wt,
    const float* __restrict__ bias,
    float* __restrict__ out) {
  __shared__ __align__(16) char smem[24576];

  const int tid = threadIdx.x;
  const int bid = blockIdx.x;
  const int ft    = bid & 1;
  const int wtile = (bid >> 1) & 1;
  const int h     = (bid >> 2) & 127;
  const int n     = bid >> 9;
  const int f0 = ft * 128;
  const int w0 = wtile * 64;
  const int p  = h & 1;
  const int tap0   = p ? 7 : 0;
  const int nsteps = p ? 8 : 14;   // taps * (128/64)

  const int lane = tid & 63;
  const int wid  = tid >> 6;
  const int l16  = lane & 15;
  const int lk   = lane >> 4;

  // A-stage map: thread -> (row awl 0..63, 16-channel chunk ag2 0..3)
  const int awl = tid >> 2;
  const int ag2 = tid & 3;
  // B-stage map: thread -> (row bfl 0..127, 32-channel half 0..1)
  const int bfl   = tid >> 1;
  const int bhalf = tid & 1;

  float4 ar0, ar1, ar2, ar3;   // 16 fp32 of x
  uint4  br0, br1, br2, br3;   // 32 bf16 of wt

  auto load_step = [&](int s) {
    const int tap = tap0 + (s >> 1);
    const int cc  = s & 1;
    int dr, dc, kr, kc;
    tap_info(tap, dr, dc, kr, kc);
    const int hh = h + dr;
    const int wg = w0 + awl + dc;           // input column
    const bool av = (hh < H_) && (wg >= 0) && (wg < W_);
    if (av) {
      const float* ap = x + (((long)(n * H_ + hh) * W_ + wg) * C_ + cc * 64 + ag2 * 16);
      ar0 = *(const float4*)(ap);
      ar1 = *(const float4*)(ap + 4);
      ar2 = *(const float4*)(ap + 8);
      ar3 = *(const float4*)(ap + 12);
    } else {
      ar0 = ar1 = ar2 = ar3 = make_float4(0.f, 0.f, 0.f, 0.f);
    }
    const unsigned short* bp =
        wt + ((size_t)(tap * F_ + f0 + bfl) * C_ + cc * 64 + bhalf * 32);
    const uint4* bq = (const uint4*)bp;
    br0 = bq[0]; br1 = bq[1]; br2 = bq[2]; br3 = bq[3];
  };

  auto write_step = [&]() {
    uint4 u0, u1;
    u0.x = pack2(ar0.x, ar0.y); u0.y = pack2(ar0.z, ar0.w);
    u0.z = pack2(ar1.x, ar1.y); u0.w = pack2(ar1.z, ar1.w);
    u1.x = pack2(ar2.x, ar2.y); u1.y = pack2(ar2.z, ar2.w);
    u1.z = pack2(ar3.x, ar3.y); u1.w = pack2(ar3.z, ar3.w);
    char* abase = (char*)smem + awl * 128;
    const int sw = awl & 7;
    *(uint4*)(abase + (((2 * ag2)     ^ sw) * 16)) = u0;
    *(uint4*)(abase + (((2 * ag2 + 1) ^ sw) * 16)) = u1;
    char* bbase = (char*)smem + 8192 + bfl * 128;
    const int sb = bfl & 7;
    *(uint4*)(bbase + (((bhalf * 4 + 0) ^ sb) * 16)) = br0;
    *(uint4*)(bbase + (((bhalf * 4 + 1) ^ sb) * 16)) = br1;
    *(uint4*)(bbase + (((bhalf * 4 + 2) ^ sb) * 16)) = br2;
    *(uint4*)(bbase + (((bhalf * 4 + 3) ^ sb) * 16)) = br3;
  };

  f32x4 acc[4][2] = {};

  load_step(0);
  for (int s = 0; s < nsteps; ++s) {
    __syncthreads();      // previous compute done -> LDS reusable
    write_step();
    __syncthreads();      // tile visible
    if (s + 1 < nsteps) load_step(s + 1);   // overlap next loads with compute

    const char* ab = (const char*)smem;
    const char* bb = (const char*)smem + 8192;
    bf16x8 af[4][2], bfr[2][2];
#pragma unroll
    for (int m = 0; m < 4; ++m)
#pragma unroll
      for (int kkk = 0; kkk < 2; ++kkk) {
        const int wl = m * 16 + l16;
        const int g  = (kkk * 4 + lk) ^ (wl & 7);
        af[m][kkk] = *(const bf16x8*)(ab + wl * 128 + g * 16);
      }
#pragma unroll
    for (int fi = 0; fi < 2; ++fi)
#pragma unroll
      for (int kkk = 0; kkk < 2; ++kkk) {
        const int fl = wid * 32 + fi * 16 + l16;
        const int g  = (kkk * 4 + lk) ^ (fl & 7);
        bfr[fi][kkk] = *(const bf16x8*)(bb + fl * 128 + g * 16);
      }
#pragma unroll
    for (int m = 0; m < 4; ++m)
#pragma unroll
      for (int fi = 0; fi < 2; ++fi)
#pragma unroll
        for (int kkk = 0; kkk < 2; ++kkk)
          acc[m][fi] = __builtin_amdgcn_mfma_f32_16x16x32_bf16(
              af[m][kkk], bfr[fi][kkk], acc[m][fi], 0, 0, 0);
  }

  // epilogue: + bias, relu, FP32 store.  D: col(f)=lane&15, row(w)=(lane>>4)*4+r
#pragma unroll
  for (int fi = 0; fi < 2; ++fi) {
    const int f = f0 + wid * 32 + fi * 16 + l16;
    const float bv = bias[f];
#pragma unroll
    for (int m = 0; m < 4; ++m) {
      const int w = w0 + m * 16 + lk * 4;
      float* o = out + (((size_t)(n * H_ + h) * W_ + w) * F_ + f);
#pragma unroll
      for (int r = 0; r < 4; ++r) {
        float v = acc[m][fi][r] + bv;
        v = v > 0.f ? v : 0.f;
        o[(size_t)r * F_] = v;
      }
    }
  }
}

extern "C" void kernel_launch(void* const* d_in, const int* in_sizes, int n_in,
                              void* d_out, int out_size, void* d_ws, size_t ws_size,
                              hipStream_t stream) {
  const float* x    = (const float*)d_in[0];
  const float* kern = (const float*)d_in[1];
  const float* bias = (const float*)d_in[2];
  float* out = (float*)d_out;
  unsigned short* wt = (unsigned short*)d_ws;   // 11*256*128*2 = 720,896 bytes

  {
    int total = 11 * F_ * C_;   // 360448
    build_w_kernel<<<(total + 255) / 256, 256, 0, stream>>>(kern, wt);
  }
  {
    int blocks = N_ * H_ * 2 * 2;   // 8192
    hconv_kernel<<<blocks, 256, 0, stream>>>(x, wt, bias, out);
  }
}

// Round 6
// 231.198 us; speedup vs baseline: 1.1593x; 1.1593x over previous
//
#include <hip/hip_runtime.h>

// Hex conv:  y[h,w,f] = relu( bias[f] + sum_taps x[h+dr, w+dc, c] * K[kr,kc][c][f] )
// parity p = h&1:
//   p==0 (7 taps): (dr,dc,kr,kc) = (0,0,0,1)(0,1,0,2)(1,-1,1,0)(1,0,1,1)(1,1,1,2)(2,0,2,1)(2,1,2,2)
//   p==1 (4 taps): (0,-1,0,1)(0,0,0,2)(1,-1,2,1)(1,0,2,2)
// x: (16,128,128,128) fp32 NHWC; K: (3,3,128,256) fp32 HWIO; bias: (256,) fp32.
// out: (16,128,128,256) fp32.

#define N_  16
#define H_  128
#define W_  128
#define C_  128
#define F_  256

typedef short bf16x8 __attribute__((ext_vector_type(8)));  // 8 bf16 in 4 VGPRs
typedef float f32x4  __attribute__((ext_vector_type(4)));

__device__ __forceinline__ unsigned int bf_bits(float f) {
  unsigned int u = __float_as_uint(f);
  return (u + 0x7FFFu + ((u >> 16) & 1u)) >> 16;   // RNE fp32 -> bf16
}
__device__ __forceinline__ unsigned int pack2(float a, float b) {
  return bf_bits(a) | (bf_bits(b) << 16);
}

__device__ __forceinline__ void tap_info(int t, int& dr, int& dc, int& kr, int& kc) {
  switch (t) {
    case 0:  dr = 0; dc = 0;  kr = 0; kc = 1; break;
    case 1:  dr = 0; dc = 1;  kr = 0; kc = 2; break;
    case 2:  dr = 1; dc = -1; kr = 1; kc = 0; break;
    case 3:  dr = 1; dc = 0;  kr = 1; kc = 1; break;
    case 4:  dr = 1; dc = 1;  kr = 1; kc = 2; break;
    case 5:  dr = 2; dc = 0;  kr = 2; kc = 1; break;
    case 6:  dr = 2; dc = 1;  kr = 2; kc = 2; break;
    case 7:  dr = 0; dc = -1; kr = 0; kc = 1; break;
    case 8:  dr = 0; dc = 0;  kr = 0; kc = 2; break;
    case 9:  dr = 1; dc = -1; kr = 2; kc = 1; break;
    default: dr = 1; dc = 0;  kr = 2; kc = 2; break;
  }
}

// ---------------- prep: packed transposed weights ----------------
// wt[t][f][c] (c contiguous, bf16 bits) = kernel[kr(t)][kc(t)][c][f]
__global__ __launch_bounds__(256) void build_w_kernel(
    const float* __restrict__ k, unsigned short* __restrict__ wt) {
  int tid = blockIdx.x * 256 + threadIdx.x;
  if (tid >= 11 * F_ * C_) return;
  int c = tid & 127;
  int f = (tid >> 7) & 255;
  int t = tid >> 15;
  int dr, dc, kr, kc;
  tap_info(t, dr, dc, kr, kc);
  float v = k[((kr * 3 + kc) * C_ + c) * F_ + f];
  wt[tid] = (unsigned short)bf_bits(v);
}

// ---------------- main conv: implicit GEMM, MFMA 16x16x32 bf16 ----------------
// block = 256 thr (4 waves); tile = 64(w) x 128(f); K-step = 64 channels
// LDS (double-buffered): A0 @0, A1 @8192 (8KB each); B0 @16384, B1 @32768 (16KB each)
// 16B groups within each row XOR-swizzled by (row&7) on BOTH write and read.
// Schedule: one barrier per K-step; ds-writes of step s+1 overlap MFMA of s;
// global loads for s+2 issued during s (full step of latency cover).
__global__ __launch_bounds__(256, 3) void hconv_kernel(
    const float* __restrict__ x,
    const unsigned short* __restrict__ wt,
    const float* __restrict__ bias,
    float* __restrict__ out) {
  __shared__ __align__(16) char smem[49152];

  const int tid = threadIdx.x;
  // XCD-aware bijective swizzle: grid 8192 = 8 * 1024
  const int bid = (blockIdx.x & 7) * 1024 + (blockIdx.x >> 3);
  const int ft    = bid & 1;
  const int wtile = (bid >> 1) & 1;
  const int h     = (bid >> 2) & 127;
  const int n     = bid >> 9;
  const int f0 = ft * 128;
  const int w0 = wtile * 64;
  const int p  = h & 1;
  const int tap0   = p ? 7 : 0;
  const int nsteps = p ? 8 : 14;   // taps * (128/64)

  const int lane = tid & 63;
  const int wid  = tid >> 6;
  const int l16  = lane & 15;
  const int lk   = lane >> 4;

  // A-stage map: thread -> (row awl 0..63, 16-channel chunk ag2 0..3)
  const int awl = tid >> 2;
  const int ag2 = tid & 3;
  // B-stage map: thread -> (row bfl 0..127, 32-channel half 0..1)
  const int bfl   = tid >> 1;
  const int bhalf = tid & 1;

  float4 ar0, ar1, ar2, ar3;   // 16 fp32 of x
  uint4  br0, br1, br2, br3;   // 32 bf16 of wt

  auto load_step = [&](int s) {
    const int tap = tap0 + (s >> 1);
    const int cc  = s & 1;
    int dr, dc, kr, kc;
    tap_info(tap, dr, dc, kr, kc);
    const int hh = h + dr;
    const int wg = w0 + awl + dc;           // input column
    const bool av = (hh < H_) && (wg >= 0) && (wg < W_);
    if (av) {
      const float* ap = x + (((long)(n * H_ + hh) * W_ + wg) * C_ + cc * 64 + ag2 * 16);
      ar0 = *(const float4*)(ap);
      ar1 = *(const float4*)(ap + 4);
      ar2 = *(const float4*)(ap + 8);
      ar3 = *(const float4*)(ap + 12);
    } else {
      ar0 = ar1 = ar2 = ar3 = make_float4(0.f, 0.f, 0.f, 0.f);
    }
    const unsigned short* bp =
        wt + ((size_t)(tap * F_ + f0 + bfl) * C_ + cc * 64 + bhalf * 32);
    const uint4* bq = (const uint4*)bp;
    br0 = bq[0]; br1 = bq[1]; br2 = bq[2]; br3 = bq[3];
  };

  auto write_step = [&](int sel) {
    uint4 u0, u1;
    u0.x = pack2(ar0.x, ar0.y); u0.y = pack2(ar0.z, ar0.w);
    u0.z = pack2(ar1.x, ar1.y); u0.w = pack2(ar1.z, ar1.w);
    u1.x = pack2(ar2.x, ar2.y); u1.y = pack2(ar2.z, ar2.w);
    u1.z = pack2(ar3.x, ar3.y); u1.w = pack2(ar3.z, ar3.w);
    char* abase = (char*)smem + sel * 8192 + awl * 128;
    const int sw = awl & 7;
    *(uint4*)(abase + (((2 * ag2)     ^ sw) * 16)) = u0;
    *(uint4*)(abase + (((2 * ag2 + 1) ^ sw) * 16)) = u1;
    char* bbase = (char*)smem + 16384 + sel * 16384 + bfl * 128;
    const int sb = bfl & 7;
    *(uint4*)(bbase + (((bhalf * 4 + 0) ^ sb) * 16)) = br0;
    *(uint4*)(bbase + (((bhalf * 4 + 1) ^ sb) * 16)) = br1;
    *(uint4*)(bbase + (((bhalf * 4 + 2) ^ sb) * 16)) = br2;
    *(uint4*)(bbase + (((bhalf * 4 + 3) ^ sb) * 16)) = br3;
  };

  f32x4 acc[4][2] = {};

  // Pipeline prologue: r(0) -> buf0, r(1) in regs
  load_step(0);
  write_step(0);
  load_step(1);
  __syncthreads();

  for (int s = 0; s < nsteps; ++s) {
    const int cur = s & 1;
    const char* ab = (const char*)smem + cur * 8192;
    const char* bb = (const char*)smem + 16384 + cur * 16384;

    // fragment reads from current buffer
    bf16x8 af[4][2], bfr[2][2];
#pragma unroll
    for (int m = 0; m < 4; ++m)
#pragma unroll
      for (int kkk = 0; kkk < 2; ++kkk) {
        const int wl = m * 16 + l16;
        const int g  = (kkk * 4 + lk) ^ (wl & 7);
        af[m][kkk] = *(const bf16x8*)(ab + wl * 128 + g * 16);
      }
#pragma unroll
    for (int fi = 0; fi < 2; ++fi)
#pragma unroll
      for (int kkk = 0; kkk < 2; ++kkk) {
        const int fl = wid * 32 + fi * 16 + l16;
        const int g  = (kkk * 4 + lk) ^ (fl & 7);
        bfr[fi][kkk] = *(const bf16x8*)(bb + fl * 128 + g * 16);
      }

    // stage r(s+1) into the other buffer (overlaps MFMA below)
    if (s + 1 < nsteps) write_step(cur ^ 1);
    // refill regs with r(s+2)
    if (s + 2 < nsteps) load_step(s + 2);

#pragma unroll
    for (int m = 0; m < 4; ++m)
#pragma unroll
      for (int fi = 0; fi < 2; ++fi)
#pragma unroll
        for (int kkk = 0; kkk < 2; ++kkk)
          acc[m][fi] = __builtin_amdgcn_mfma_f32_16x16x32_bf16(
              af[m][kkk], bfr[fi][kkk], acc[m][fi], 0, 0, 0);

    __syncthreads();
  }

  // epilogue: + bias, relu, fp32 store.  D: col(f)=lane&15, row(w)=(lane>>4)*4+r
#pragma unroll
  for (int fi = 0; fi < 2; ++fi) {
    const int f = f0 + wid * 32 + fi * 16 + l16;
    const float bv = bias[f];
#pragma unroll
    for (int m = 0; m < 4; ++m) {
      const int w = w0 + m * 16 + lk * 4;
      float* o = out + (((size_t)(n * H_ + h) * W_ + w) * F_ + f);
#pragma unroll
      for (int r = 0; r < 4; ++r) {
        float v = acc[m][fi][r] + bv;
        v = v > 0.f ? v : 0.f;
        o[(size_t)r * F_] = v;
      }
    }
  }
}

extern "C" void kernel_launch(void* const* d_in, const int* in_sizes, int n_in,
                              void* d_out, int out_size, void* d_ws, size_t ws_size,
                              hipStream_t stream) {
  const float* x    = (const float*)d_in[0];
  const float* kern = (const float*)d_in[1];
  const float* bias = (const float*)d_in[2];
  float* out = (float*)d_out;
  unsigned short* wt = (unsigned short*)d_ws;   // 11*256*128*2 = 720,896 bytes

  {
    int total = 11 * F_ * C_;   // 360448
    build_w_kernel<<<(total + 255) / 256, 256, 0, stream>>>(kern, wt);
  }
  {
    int blocks = N_ * H_ * 2 * 2;   // 8192
    hconv_kernel<<<blocks, 256, 0, stream>>>(x, wt, bias, out);
  }
}